// Round 3
// baseline (273.610 us; speedup 1.0000x reference)
//
#include <hip/hip_runtime.h>
#include <cmath>

#define NTOK 1024
#define HD   768
#define FF   3072
#define NE   8
#define NSLOT (NTOK * 2)
#define BK   64

#define NB_ROUTER 256            // 4 tokens per block
#define NB_CONV   4608           // per matrix: 8 experts * 576 (64k x 64n) tiles
#define NB_FFN1   1152           // 24 m-tile capacity * 48 n-tiles
#define KSPLIT    4
#define KSEG      (FF / KSPLIT)  // 768
#define NB_FFN2   (24 * 6 * KSPLIT)  // 576 (24 mtiles * 6 n128-tiles * 4 ksplit)

typedef unsigned short u16;
typedef unsigned int   u32;
typedef __bf16 bf16x8 __attribute__((ext_vector_type(8)));
typedef float  f32x4  __attribute__((ext_vector_type(4)));
typedef u16    u16x8  __attribute__((ext_vector_type(8)));

__device__ __forceinline__ u16 f2bf(float f) {
  union { float f; u32 u; } v; v.f = f;
  u32 r = v.u + 0x7FFFu + ((v.u >> 16) & 1u);
  return (u16)(r >> 16);
}

// global->LDS direct DMA, 16B per lane. LDS dest wave-uniform base; HW writes
// base + lane*16. Global address is per-lane (gather OK). Zero VGPR cost ->
// latency hidden by vmcnt queue depth, not register count.
__device__ __forceinline__ void load16(const void* g, void* l) {
  __builtin_amdgcn_global_load_lds(
      (const __attribute__((address_space(1))) u32*)g,
      (__attribute__((address_space(3))) u32*)l, 16, 0, 0);
}

// ---------------------------------------------------------------------------
// Convert one 64k x 64n tile: fp32 [K][N] -> bf16 [N][K], DMA-staged.
// LDS holds fp32 [64k][64n] with column XOR-swizzle: LDS[k][p] = src[k][p^sx(k)],
// sx(k) = ((k>>3)&3)<<3. Swizzle applied on the GLOBAL source (DMA dest is
// linear); the transposing read applies the same involution -> 2-way max bank
// aliasing (free). Output: each wave store instr covers full 128B rows.
// ---------------------------------------------------------------------------
__device__ __forceinline__ void conv_tile_dma(
    const float* __restrict__ src, u16* __restrict__ dst,
    int K, int N, int k0, int n0, float* lt, int tid, int lane, int wid)
{
  const int kr = wid * 16;
#pragma unroll
  for (int j = 0; j < 4; ++j) {
    const int k  = kr + j * 4 + (lane >> 4);               // per-lane k row
    const int sc = ((lane & 15) * 4) ^ (((k >> 3) & 3) << 3); // swizzled src col
    load16(src + (size_t)(k0 + k) * N + n0 + sc,
           lt + (size_t)(kr + j * 4) * 64);                // uniform base; +lane*16
  }
  __syncthreads();
#pragma unroll
  for (int h = 0; h < 2; ++h) {
    const int c  = tid + h * 256;     // chunk id: n = c>>3, k-octet = c&7
    const int n  = c >> 3;
    const int ko = c & 7;
    const int sx = (ko & 3) << 3;     // = ((k>>3)&3)<<3 for k in this octet
    u16x8 vv;
#pragma unroll
    for (int d = 0; d < 8; ++d)
      vv[d] = f2bf(lt[(ko * 8 + d) * 64 + (n ^ sx)]);
    *(u16x8*)(dst + (size_t)(n0 + n) * K + k0 + ko * 8) = vv;
  }
}

// ---------------------------------------------------------------------------
// K1: router (blocks [0,256)) + w1 convert (blocks [256, 256+4608)).
// Router blocks also zero `out` (12KB each) and the LAST router block to
// finish runs the scatter (counts + prefix + slot assignment) -- eliminates
// the separate scatter kernel, the counts memset, and the out memset.
// Cross-XCD visibility: __threadfence (agent acq/rel) around the done-counter.
// ---------------------------------------------------------------------------
__global__ __launch_bounds__(256) void conv1_router_kernel(
    const float* __restrict__ w1, u16* __restrict__ w1t,
    const float* __restrict__ x, const float* __restrict__ rw,
    u16* __restrict__ xb, int* __restrict__ ti, float* __restrict__ tg,
    int* __restrict__ tos, float* __restrict__ gos, int* __restrict__ seg,
    int* __restrict__ done, float* __restrict__ out)
{
  __shared__ __align__(16) float lt[64 * 64];   // 16384 B (conv path)
  __shared__ int soff[NE], scnt[NE], spos[NE], lastFlag;
  const int tid  = threadIdx.x;
  const int lane = tid & 63;
  const int wid  = tid >> 6;

  if (blockIdx.x >= NB_ROUTER) {
    const int cid = blockIdx.x - NB_ROUTER;
    const int z   = cid / 576;
    const int rem = cid % 576;
    conv_tile_dma(w1 + (size_t)z * HD * FF, w1t + (size_t)z * FF * HD,
                  HD, FF, (rem / 48) * 64, (rem % 48) * 64, lt, tid, lane, wid);
    return;
  }

  // ---- zero a 12KB slice of out (replaces hipMemsetAsync(d_out)) ----
  {
    float4* o4 = (float4*)out;
    const float4 zz = {0.f, 0.f, 0.f, 0.f};
#pragma unroll
    for (int i = 0; i < 3; ++i) o4[(size_t)blockIdx.x * 768 + i * 256 + tid] = zz;
  }

  // ---- router: logits + top2 for 4 tokens (one per wave) ----
  const int t = blockIdx.x * 4 + wid;
  const float* xrow = x + (size_t)t * HD;
  u16* xbrow = xb + (size_t)t * HD;

  float acc[NE] = {};
#pragma unroll
  for (int j = 0; j < 12; ++j) {
    const int h = lane + j * 64;
    const float xv = xrow[h];
    xbrow[h] = f2bf(xv);
    const float4 r0 = *(const float4*)(rw + h * 8);
    const float4 r1 = *(const float4*)(rw + h * 8 + 4);
    acc[0] += xv * r0.x; acc[1] += xv * r0.y;
    acc[2] += xv * r0.z; acc[3] += xv * r0.w;
    acc[4] += xv * r1.x; acc[5] += xv * r1.y;
    acc[6] += xv * r1.z; acc[7] += xv * r1.w;
  }
#pragma unroll
  for (int e = 0; e < NE; ++e) {
    float v = acc[e];
#pragma unroll
    for (int off = 32; off; off >>= 1) v += __shfl_down(v, off, 64);
    acc[e] = v;
  }
  if (lane == 0) {
    float v0 = -1e30f, v1 = -1e30f; int i0 = 0, i1 = 0;
#pragma unroll
    for (int e = 0; e < NE; ++e) {
      const float p = acc[e];
      if (p > v0) { v1 = v0; i1 = i0; v0 = p; i0 = e; }
      else if (p > v1) { v1 = p; i1 = e; }
    }
    const float e1 = expf(v1 - v0);
    ti[2 * t] = i0;      ti[2 * t + 1] = i1;
    tg[2 * t] = 1.0f / (1.0f + e1);
    tg[2 * t + 1] = e1 / (1.0f + e1);
  }

  // ---- completion counter; last block runs the scatter ----
  __syncthreads();                 // all block stores issued & drained
  __threadfence();                 // agent release (L2 writeback)
  if (tid == 0) lastFlag = (atomicAdd(done, 1) == NB_ROUTER - 1);
  __syncthreads();
  if (!lastFlag) return;
  __threadfence();                 // agent acquire (invalidate stale cache)

  // ---- scatter: 2048 slots, 8 per thread ----
  if (tid < NE) scnt[tid] = 0;
  __syncthreads();
  int   mye[8]; float myg[8];
#pragma unroll
  for (int j = 0; j < 8; ++j) {
    const int s = tid * 8 + j;
    mye[j] = ti[s]; myg[j] = tg[s];
    atomicAdd(&scnt[mye[j]], 1);
  }
  __syncthreads();
  if (tid == 0) {
    int o = 0;
    for (int e = 0; e < NE; ++e) {
      soff[e] = o; seg[e] = o; seg[NE + e] = scnt[e]; o += scnt[e];
    }
  }
  if (tid < NE) spos[tid] = 0;
  __syncthreads();
#pragma unroll
  for (int j = 0; j < 8; ++j) {
    const int s = tid * 8 + j;
    const int p = atomicAdd(&spos[mye[j]], 1);
    const int o = soff[mye[j]] + p;
    tos[o] = s >> 1;     // token
    gos[o] = myg[j];
  }
}

// expert lookup for capacity grids: mt -> (e, m0); e stays -1 past the end.
__device__ __forceinline__ int find_expert(const int* __restrict__ seg,
                                           int mt, int* m0_out) {
  int e = -1, m0 = 0, off = 0;
#pragma unroll
  for (int ee = 0; ee < NE; ++ee) {
    const int T = (seg[NE + ee] + 127) >> 7;
    if (e < 0 && mt < off + T) { e = ee; m0 = (mt - off) << 7; }
    off += T;
  }
  *m0_out = m0;
  return e;
}

// ---------------------------------------------------------------------------
// K3: ffn1 (MFMA, capacity grid 1152) fused 1:4 with w2 convert (4608 tiles).
// ffn1: 128m x 64n, BK=64, 4 waves (2x2 over 64x32, acc 4x2), global_load_lds
// staging, XOR-swizzled unpadded LDS (phys 16B chunk = logical ^ (row&7)).
// ---------------------------------------------------------------------------
__global__ __launch_bounds__(256) void ffn1_conv2_kernel(
    const u16* __restrict__ xb, const u16* __restrict__ w1t,
    const int* __restrict__ tos, const int* __restrict__ seg,
    u16* __restrict__ hbuf,
    const float* __restrict__ w2, u16* __restrict__ w2t)
{
  __shared__ __align__(16) char smem[25088];   // ffn1 25088 / conv 16384
  const int tid  = threadIdx.x;
  const int lane = tid & 63;
  const int wid  = tid >> 6;

  const int g  = blockIdx.x / 5;
  const int r5 = blockIdx.x % 5;

  if (r5) {
    const int cid = g * 4 + (r5 - 1);
    const int z   = cid / 576;
    const int rem = cid % 576;
    conv_tile_dma(w2 + (size_t)z * FF * HD, w2t + (size_t)z * HD * FF,
                  FF, HD, (rem % 48) * 64, (rem / 48) * 64,
                  (float*)smem, tid, lane, wid);
    return;
  }

  const int mt = g / 48, nt = g % 48;
  int m0;
  const int e = find_expert(seg, mt, &m0);
  if (e < 0) return;
  const int cnt   = seg[NE + e];
  const int start = seg[e];
  const int n0    = nt * 64;

  u16* As   = (u16*)smem;              // 16384
  u16* Bs   = (u16*)(smem + 16384);    //  8192
  int* toks = (int*)(smem + 24576);    //   512

  if (tid < 128) toks[tid] = tos[start + min(m0 + tid, cnt - 1)];
  __syncthreads();

  const int rsub = lane >> 3;
  const int c8   = (lane & 7) ^ rsub;

  const u16* ag[4]; u16* al[4];
#pragma unroll
  for (int i = 0; i < 4; ++i) {
    const int rb = wid * 8 + i * 32;
    ag[i] = xb + (size_t)toks[rb + rsub] * HD + c8 * 8;
    al[i] = As + rb * 64;
  }
  const u16* bg[2]; u16* bl[2];
#pragma unroll
  for (int i = 0; i < 2; ++i) {
    const int rb = wid * 8 + i * 32;
    bg[i] = w1t + ((size_t)e * FF + n0 + rb + rsub) * HD + c8 * 8;
    bl[i] = Bs + rb * 64;
  }

  const int wm  = (wid >> 1) << 6;
  const int wn  = (wid & 1) << 5;
  const int q   = lane >> 4;
  const int r16 = lane & 15;

  f32x4 acc[4][2] = {};

  for (int k0 = 0; k0 < HD; k0 += BK) {
#pragma unroll
    for (int i = 0; i < 4; ++i) load16(ag[i] + k0, al[i]);
#pragma unroll
    for (int i = 0; i < 2; ++i) load16(bg[i] + k0, bl[i]);
    __syncthreads();
#pragma unroll
    for (int s = 0; s < 2; ++s) {
      const int pa = ((s << 2) + q) ^ (r16 & 7);
      bf16x8 af[4], bf[2];
#pragma unroll
      for (int t = 0; t < 4; ++t)
        af[t] = *(const bf16x8*)(&As[(wm + t * 16 + r16) * 64 + pa * 8]);
#pragma unroll
      for (int t = 0; t < 2; ++t)
        bf[t] = *(const bf16x8*)(&Bs[(wn + t * 16 + r16) * 64 + pa * 8]);
#pragma unroll
      for (int t = 0; t < 4; ++t)
#pragma unroll
        for (int c = 0; c < 2; ++c)
          acc[t][c] = __builtin_amdgcn_mfma_f32_16x16x32_bf16(af[t], bf[c], acc[t][c], 0, 0, 0);
    }
    __syncthreads();
  }

#pragma unroll
  for (int t = 0; t < 4; ++t) {
    const int mbase = m0 + wm + t * 16 + q * 4;
#pragma unroll
    for (int i = 0; i < 4; ++i) {
      if (mbase + i < cnt) {
        u16* drow = hbuf + (size_t)(start + mbase + i) * FF + n0 + wn;
#pragma unroll
        for (int c = 0; c < 2; ++c) {
          float v = acc[t][c][i];
          v = 0.5f * v * (1.0f + erff(v * 0.70710678118f));
          drow[c * 16 + r16] = f2bf(v);
        }
      }
    }
  }
}

// ---------------------------------------------------------------------------
// K4: ffn2, 128m x 128n tiles (halves hbuf re-reads), K-split x4, capacity
// grid 576, atomic fp32 accumulate into out. 4 waves 2x2 over 64x64, acc 4x4.
// ---------------------------------------------------------------------------
__global__ __launch_bounds__(256) void ffn2_kernel(
    const u16* __restrict__ hbuf, const u16* __restrict__ w2t,
    const int* __restrict__ tos, const float* __restrict__ gos,
    const int* __restrict__ seg, float* __restrict__ out)
{
  const int fid  = blockIdx.x;
  const int mt   = fid / 24;
  const int rest = fid % 24;
  const int n0   = (rest >> 2) << 7;   // 0..640 step 128
  const int ks   = rest & 3;
  int m0;
  const int e = find_expert(seg, mt, &m0);
  if (e < 0) return;
  const int cnt   = seg[NE + e];
  const int start = seg[e];
  const int kbase = ks * KSEG;

  __shared__ __align__(16) u16 As[128 * 64];   // 16384
  __shared__ __align__(16) u16 Bs[128 * 64];   // 16384
  __shared__ int   toks[128];
  __shared__ float gates[128];

  const int tid = threadIdx.x;
  if (tid < 128) {
    const int idx = start + min(m0 + tid, cnt - 1);
    toks[tid]  = tos[idx];
    gates[tid] = gos[idx];
  }
  __syncthreads();

  const int lane = tid & 63;
  const int wid  = tid >> 6;
  const int rsub = lane >> 3;
  const int c8   = (lane & 7) ^ rsub;

  const u16* ag[4]; u16* al[4];
#pragma unroll
  for (int i = 0; i < 4; ++i) {
    const int rb = wid * 8 + i * 32;
    ag[i] = hbuf + (size_t)(start + min(m0 + rb + rsub, cnt - 1)) * FF + kbase + c8 * 8;
    al[i] = As + rb * 64;
  }
  const u16* bg[4]; u16* bl[4];
#pragma unroll
  for (int i = 0; i < 4; ++i) {
    const int rb = wid * 8 + i * 32;
    bg[i] = w2t + ((size_t)e * HD + n0 + rb + rsub) * FF + kbase + c8 * 8;
    bl[i] = Bs + rb * 64;
  }

  const int wm  = (wid >> 1) << 6;   // 0 / 64 (m)
  const int wn  = (wid & 1) << 6;    // 0 / 64 (n)
  const int q   = lane >> 4;
  const int r16 = lane & 15;

  f32x4 acc[4][4] = {};

  for (int k0 = 0; k0 < KSEG; k0 += BK) {
#pragma unroll
    for (int i = 0; i < 4; ++i) load16(ag[i] + k0, al[i]);
#pragma unroll
    for (int i = 0; i < 4; ++i) load16(bg[i] + k0, bl[i]);
    __syncthreads();
#pragma unroll
    for (int s = 0; s < 2; ++s) {
      const int pa = ((s << 2) + q) ^ (r16 & 7);
      bf16x8 af[4], bf[4];
#pragma unroll
      for (int t = 0; t < 4; ++t)
        af[t] = *(const bf16x8*)(&As[(wm + t * 16 + r16) * 64 + pa * 8]);
#pragma unroll
      for (int c = 0; c < 4; ++c)
        bf[c] = *(const bf16x8*)(&Bs[(wn + c * 16 + r16) * 64 + pa * 8]);
#pragma unroll
      for (int t = 0; t < 4; ++t)
#pragma unroll
        for (int c = 0; c < 4; ++c)
          acc[t][c] = __builtin_amdgcn_mfma_f32_16x16x32_bf16(af[t], bf[c], acc[t][c], 0, 0, 0);
    }
    __syncthreads();
  }

#pragma unroll
  for (int t = 0; t < 4; ++t) {
    const int mbase = wm + t * 16 + q * 4;
#pragma unroll
    for (int i = 0; i < 4; ++i) {
      const int mloc = mbase + i;
      if (m0 + mloc < cnt) {
        const int tok  = toks[mloc];
        const float gv = gates[mloc];
        float* drow = out + (size_t)tok * HD + n0 + wn;
#pragma unroll
        for (int c = 0; c < 4; ++c)
          atomicAdd(drow + c * 16 + r16, gv * acc[t][c][i]);
      }
    }
  }
}

// ---------------------------------------------------------------------------
extern "C" void kernel_launch(void* const* d_in, const int* in_sizes, int n_in,
                              void* d_out, int out_size, void* d_ws, size_t ws_size,
                              hipStream_t stream) {
  const float* x  = (const float*)d_in[0];
  const float* rw = (const float*)d_in[1];
  const float* w1 = (const float*)d_in[2];
  const float* w2 = (const float*)d_in[3];
  float* out = (float*)d_out;

  char* ws = (char*)d_ws;
  const size_t o_xb    = 0;
  const size_t o_hbuf  = o_xb + (size_t)NTOK * HD * 2;
  const size_t o_tos   = o_hbuf + (size_t)NSLOT * FF * 2;
  const size_t o_gos   = o_tos + (size_t)NSLOT * 4;
  const size_t o_seg   = o_gos + (size_t)NSLOT * 4;
  const size_t o_done  = o_seg + 64 * 4;
  const size_t o_ti    = o_done + 64;
  const size_t o_tg    = o_ti + (size_t)NSLOT * 4;
  const size_t o_w1t   = (o_tg + (size_t)NSLOT * 4 + 255) & ~(size_t)255;
  const size_t o_w2t   = o_w1t + (size_t)NE * HD * FF * 2;
  u16*   xb    = (u16*)(ws + o_xb);
  u16*   hbuf  = (u16*)(ws + o_hbuf);
  int*   tos   = (int*)(ws + o_tos);
  float* gos   = (float*)(ws + o_gos);
  int*   seg   = (int*)(ws + o_seg);
  int*   done  = (int*)(ws + o_done);
  int*   ti    = (int*)(ws + o_ti);
  float* tg    = (float*)(ws + o_tg);
  u16*   w1t   = (u16*)(ws + o_w1t);
  u16*   w2t   = (u16*)(ws + o_w2t);

  hipMemsetAsync(done, 0, 64, stream);
  hipLaunchKernelGGL(conv1_router_kernel, dim3(NB_ROUTER + NB_CONV), dim3(256), 0, stream,
                     w1, w1t, x, rw, xb, ti, tg, tos, gos, seg, done, out);
  hipLaunchKernelGGL(ffn1_conv2_kernel, dim3(NB_FFN1 * 5), dim3(256), 0, stream,
                     xb, w1t, tos, seg, hbuf, w2, w2t);
  hipLaunchKernelGGL(ffn2_kernel, dim3(NB_FFN2), dim3(256), 0, stream,
                     hbuf, w2t, tos, gos, seg, out);
}